// Round 2
// baseline (228.253 us; speedup 1.0000x reference)
//
#include <hip/hip_runtime.h>
#include <math.h>

#define NS 512
#define NU 32
#define ND 512
#define GEPS 1e-6f

typedef float f4 __attribute__((ext_vector_type(4)));

// ws layout: centT [ND][NS] floats (1 MiB) | cn2 [NS] floats (2 KiB)

__global__ __launch_bounds__(256) void centroid_kernel(const float* __restrict__ dvecs,
                                                       float* __restrict__ centT,
                                                       float* __restrict__ cn2) {
    const int s = blockIdx.x;
    const int t = threadIdx.x;
    const float* base = dvecs + (size_t)s * NU * ND;
    const int d0 = t * 2;
    float ax = 0.f, ay = 0.f;
    for (int u = 0; u < NU; ++u) {
        float2 v = *(const float2*)(base + u * ND + d0);
        ax += v.x; ay += v.y;
    }
    ax *= (1.0f / NU); ay *= (1.0f / NU);
    centT[(size_t)d0 * NS + s]       = ax;   // transposed store; 1 MiB, L2-absorbed
    centT[(size_t)(d0 + 1) * NS + s] = ay;
    float c = ax * ax + ay * ay;
    for (int m = 1; m < 64; m <<= 1) c += __shfl_xor(c, m, 64);
    __shared__ float red[4];
    if ((t & 63) == 0) red[t >> 6] = c;
    __syncthreads();
    if (t == 0) cn2[s] = red[0] + red[1] + red[2] + red[3];
}

// One block per speaker: 32x512 logits tile, fused norms + LOO diagonal +
// softmax + loss. 256 thr: cg=tid&63 (cols n*256+cg*4+m), rg=tid>>6 (8 rows).
// Per-thread 8x8 tile -> LDS/VALU pipe ratio ~1 (was 2.1 at 4x16).
__global__ __launch_bounds__(256) void ge2e_kernel(const float* __restrict__ dvecs,
                                                   const float* __restrict__ centT,
                                                   const float* __restrict__ cn2,
                                                   const float* __restrict__ wp,
                                                   const float* __restrict__ bp,
                                                   float* __restrict__ out) {
    const int s   = blockIdx.x;
    const int tid = threadIdx.x;
    const int cg  = tid & 63;   // col lane: cols {n*256 + cg*4 + m}, n<2, m<4
    const int rg  = tid >> 6;   // wave index: rows rg*8 .. rg*8+7

    __shared__ float Bs[8][512];     // 16 KiB
    __shared__ float As[32][8];      // 1 KiB
    __shared__ float sSelf[32];
    __shared__ float sLoss[4];

    float acc[8][8];
    #pragma unroll
    for (int i = 0; i < 8; ++i)
        #pragma unroll
        for (int x = 0; x < 8; ++x) acc[i][x] = 0.f;
    float dn2[8];
    #pragma unroll
    for (int i = 0; i < 8; ++i) dn2[i] = 0.f;

    const float* Abase = dvecs + (size_t)s * (NU * ND);

    for (int kt = 0; kt < ND / 8; ++kt) {
        const int k0 = kt * 8;
        // stage B tile: centT[k0..k0+8][0..512), coalesced float4
        #pragma unroll
        for (int p = 0; p < 4; ++p) {
            int f  = tid + p * 256;
            int kr = f >> 7, c4 = (f & 127) * 4;
            *(f4*)&Bs[kr][c4] = *(const f4*)(centT + (size_t)(k0 + kr) * NS + c4);
        }
        // stage A tile: 32 rows x 8 k
        if (tid < 64) {
            int row = tid >> 1, c4 = (tid & 1) * 4;
            *(f4*)&As[row][c4] = *(const f4*)(Abase + row * ND + k0 + c4);
        }
        __syncthreads();
        #pragma unroll
        for (int h = 0; h < 2; ++h) {
            f4 a4[8];                                  // A fragment, b128 broadcast reads
            #pragma unroll
            for (int i = 0; i < 8; ++i) a4[i] = *(const f4*)&As[rg * 8 + i][h * 4];
            #pragma unroll
            for (int i = 0; i < 8; ++i)
                dn2[i] += a4[i][0]*a4[i][0] + a4[i][1]*a4[i][1]
                        + a4[i][2]*a4[i][2] + a4[i][3]*a4[i][3];
            #pragma unroll
            for (int kk2 = 0; kk2 < 4; ++kk2) {        // static index into a4 after unroll
                const int kk = h * 4 + kk2;
                f4 b0 = *(const f4*)&Bs[kk][cg * 4];          // conflict-free b128
                f4 b1 = *(const f4*)&Bs[kk][256 + cg * 4];
                float bf[8] = {b0[0], b0[1], b0[2], b0[3], b1[0], b1[1], b1[2], b1[3]};
                #pragma unroll
                for (int i = 0; i < 8; ++i) {
                    const float av = a4[i][kk2];
                    #pragma unroll
                    for (int x = 0; x < 8; ++x) acc[i][x] += av * bf[x];
                }
            }
        }
        __syncthreads();
    }

    // ---- epilogue: logits (in-place in acc) + LOO diagonal + softmax + loss ----
    const float w = wp[0], bb = bp[0];
    f4 c0 = *(const f4*)(cn2 + cg * 4);
    f4 c1 = *(const f4*)(cn2 + 256 + cg * 4);
    float cn2v[8] = {c0[0], c0[1], c0[2], c0[3], c1[0], c1[1], c1[2], c1[3]};
    const float cn2s  = cn2[s];
    const bool  owner = (cg == ((s & 255) >> 2));
    const int   diagx = ((s >> 8) << 2) | (s & 3);   // n*4 + m for col==s

    #pragma unroll
    for (int i = 0; i < 8; ++i) {
        const float dnv = sqrtf(dn2[i]);
        // pick raw dot at diag column without runtime-indexing acc (keeps regs)
        float dotc = 0.f;
        #pragma unroll
        for (int x = 0; x < 8; ++x) dotc = (x == diagx) ? acc[i][x] : dotc;
        const float num = (float)NU * dotc - dn2[i];
        const float X   = (float)(NU * NU) * cn2s - 2.0f * NU * dotc + dn2[i];
        const float den = fmaxf(dnv * sqrtf(X), GEPS * (NU - 1));
        const float ls  = w * (num / den) + bb;      // valid only on owner lane
        #pragma unroll
        for (int x = 0; x < 8; ++x) {
            float t = w * (acc[i][x] / fmaxf(sqrtf(dn2[i] * cn2v[x]), GEPS)) + bb;
            acc[i][x] = (owner && x == diagx) ? ls : t;
        }
        if (owner) sSelf[rg * 8 + i] = ls;
    }
    __syncthreads();

    float loss = 0.f;
    #pragma unroll
    for (int i = 0; i < 8; ++i) {
        float mx = -INFINITY;
        #pragma unroll
        for (int x = 0; x < 8; ++x) mx = fmaxf(mx, acc[i][x]);
        #pragma unroll
        for (int m = 32; m >= 1; m >>= 1) mx = fmaxf(mx, __shfl_xor(mx, m, 64));
        float se = 0.f;
        #pragma unroll
        for (int x = 0; x < 8; ++x) se += expf(acc[i][x] - mx);
        #pragma unroll
        for (int m = 32; m >= 1; m >>= 1) se += __shfl_xor(se, m, 64);
        if (cg == 0) loss += logf(se) + mx - sSelf[rg * 8 + i];
    }
    if (cg == 0) sLoss[rg] = loss;
    __syncthreads();
    if (tid == 0)
        atomicAdd(out, sLoss[0] + sLoss[1] + sLoss[2] + sLoss[3]);
}

extern "C" void kernel_launch(void* const* d_in, const int* in_sizes, int n_in,
                              void* d_out, int out_size, void* d_ws, size_t ws_size,
                              hipStream_t stream) {
    const float* dvecs = (const float*)d_in[0];
    const float* w     = (const float*)d_in[1];
    const float* b     = (const float*)d_in[2];
    float* out   = (float*)d_out;
    float* centT = (float*)d_ws;                       // 512*512 floats
    float* cn2   = centT + (size_t)ND * NS;            // 512 floats

    hipMemsetAsync(d_out, 0, sizeof(float), stream);
    centroid_kernel<<<NS, 256, 0, stream>>>(dvecs, centT, cn2);
    ge2e_kernel<<<NS, 256, 0, stream>>>(dvecs, centT, cn2, w, b, out);
}

// Round 3
// 161.690 us; speedup vs baseline: 1.4117x; 1.4117x over previous
//
#include <hip/hip_runtime.h>
#include <math.h>

#define NS 512
#define NU 32
#define ND 512
#define GEPS 1e-6f

typedef float f4 __attribute__((ext_vector_type(4)));
typedef float f32x4 __attribute__((ext_vector_type(4)));
typedef _Float16 half8 __attribute__((ext_vector_type(8)));

// ws layout: ch[NS*ND] f16 | cl[NS*ND] f16 | cn2[NS] f32 | dn2[NS*NU] f32  (~1.07 MiB)

// Fused prep: centroid mean, f16 hi/lo split of centroids, |cent|^2, exact fp32 |dvec|^2.
__global__ __launch_bounds__(256) void prep_kernel(const float* __restrict__ dvecs,
                                                   _Float16* __restrict__ ch,
                                                   _Float16* __restrict__ cl,
                                                   float* __restrict__ cn2,
                                                   float* __restrict__ dn2) {
    const int s = blockIdx.x, t = threadIdx.x;
    const float* base = dvecs + (size_t)s * NU * ND;
    __shared__ float red[2];
    if (t < 128) {
        // threads 0..127: centroid over d-slice d0..d0+3
        const int d0 = t * 4;
        f4 sum = {0.f, 0.f, 0.f, 0.f};
        for (int u = 0; u < NU; ++u) sum += *(const f4*)(base + u * ND + d0);
        float c2 = 0.f;
        short hb[4], lb[4];
        #pragma unroll
        for (int i = 0; i < 4; ++i) {
            float c = sum[i] * (1.0f / NU);
            _Float16 h  = (_Float16)c;
            _Float16 lo = (_Float16)(c - (float)h);
            hb[i] = __builtin_bit_cast(short, h);
            lb[i] = __builtin_bit_cast(short, lo);
            c2 += c * c;
        }
        short4 hs, ls;
        hs.x = hb[0]; hs.y = hb[1]; hs.z = hb[2]; hs.w = hb[3];
        ls.x = lb[0]; ls.y = lb[1]; ls.z = lb[2]; ls.w = lb[3];
        *(short4*)(ch + (size_t)s * ND + d0) = hs;
        *(short4*)(cl + (size_t)s * ND + d0) = ls;
        #pragma unroll
        for (int m = 1; m < 64; m <<= 1) c2 += __shfl_xor(c2, m);
        if ((t & 63) == 0) red[t >> 6] = c2;
    } else {
        // threads 128..255: dn2[s][u], 4 threads per u, exact fp32
        const int u = (t - 128) >> 2, j = (t - 128) & 3;
        const float* up = base + u * ND + j * 128;
        float q = 0.f;
        #pragma unroll 8
        for (int i = 0; i < 32; ++i) {
            f4 v = *(const f4*)(up + 4 * i);
            q += v[0]*v[0] + v[1]*v[1] + v[2]*v[2] + v[3]*v[3];
        }
        q += __shfl_xor(q, 1);
        q += __shfl_xor(q, 2);
        if (j == 0) dn2[s * NU + u] = q;
    }
    __syncthreads();
    if (t == 0) cn2[s] = red[0] + red[1];
}

// One block per speaker. 4 waves; wave wv owns cols [wv*128, wv*128+128).
// Per wave: 2 row-tiles x 8 col-tiles of 16x16, K=512 in 16 steps of 32.
// fp32 GEMM emulated by 4-term f16 split MFMA (error ~= fp32 rounding).
__global__ __launch_bounds__(256) void ge2e_mfma(const float* __restrict__ dvecs,
                                                 const _Float16* __restrict__ ch,
                                                 const _Float16* __restrict__ cl,
                                                 const float* __restrict__ cn2,
                                                 const float* __restrict__ dn2,
                                                 const float* __restrict__ wp,
                                                 const float* __restrict__ bp,
                                                 float* __restrict__ out) {
    const int s = blockIdx.x, tid = threadIdx.x;
    const int l = tid & 63, wv = tid >> 6;
    const int l15 = l & 15, lg = l >> 4;

    f32x4 acc[2][8];
    #pragma unroll
    for (int rt = 0; rt < 2; ++rt)
        #pragma unroll
        for (int ct = 0; ct < 8; ++ct) acc[rt][ct] = (f32x4){0.f, 0.f, 0.f, 0.f};

    const float*    Ab0 = dvecs + (size_t)s * NU * ND + (size_t)l15 * ND + lg * 8;
    const _Float16* Bh  = ch + (size_t)(wv * 128 + l15) * ND + lg * 8;
    const _Float16* Bl  = cl + (size_t)(wv * 128 + l15) * ND + lg * 8;

    for (int t = 0; t < 16; ++t) {
        const int k0 = t * 32;
        half8 ah[2], al[2];
        #pragma unroll
        for (int rt = 0; rt < 2; ++rt) {
            const float* ap = Ab0 + rt * 16 * ND + k0;
            f4 a0 = *(const f4*)ap, a1 = *(const f4*)(ap + 4);
            #pragma unroll
            for (int i = 0; i < 4; ++i) {
                _Float16 h0 = (_Float16)a0[i];
                ah[rt][i] = h0;     al[rt][i]     = (_Float16)(a0[i] - (float)h0);
                _Float16 h1 = (_Float16)a1[i];
                ah[rt][4+i] = h1;   al[rt][4+i]   = (_Float16)(a1[i] - (float)h1);
            }
        }
        #pragma unroll
        for (int ct = 0; ct < 8; ++ct) {
            half8 bh = *(const half8*)(Bh + (size_t)ct * 16 * ND + k0);
            half8 bl = *(const half8*)(Bl + (size_t)ct * 16 * ND + k0);
            #pragma unroll
            for (int rt = 0; rt < 2; ++rt) {
                acc[rt][ct] = __builtin_amdgcn_mfma_f32_16x16x32_f16(ah[rt], bh, acc[rt][ct], 0, 0, 0);
                acc[rt][ct] = __builtin_amdgcn_mfma_f32_16x16x32_f16(ah[rt], bl, acc[rt][ct], 0, 0, 0);
                acc[rt][ct] = __builtin_amdgcn_mfma_f32_16x16x32_f16(al[rt], bh, acc[rt][ct], 0, 0, 0);
                acc[rt][ct] = __builtin_amdgcn_mfma_f32_16x16x32_f16(al[rt], bl, acc[rt][ct], 0, 0, 0);
            }
        }
    }

    // ---- epilogue: C/D layout is row=(lg*4+reg)(+16*rt), col=wv*128+ct*16+l15 ----
    const float w = wp[0], bb = bp[0];
    __shared__ float sDn2[32], sSelf[32], sMax[4][32], sSum[4][32], sRow[32];
    if (tid < 32) sDn2[tid] = dn2[s * NU + tid];
    __syncthreads();
    const float cn2s = cn2[s];

    float dv[2][4];
    #pragma unroll
    for (int rt = 0; rt < 2; ++rt)
        #pragma unroll
        for (int r = 0; r < 4; ++r) dv[rt][r] = sDn2[rt * 16 + lg * 4 + r];

    const bool owner = (wv == (s >> 7)) && (l15 == (s & 15));
    const int  ctd   = (s >> 4) & 7;

    float dotc[2][4];
    #pragma unroll
    for (int ct = 0; ct < 8; ++ct)
        if (ct == ctd)                       // static index after unroll; runtime select
            #pragma unroll
            for (int rt = 0; rt < 2; ++rt)
                #pragma unroll
                for (int r = 0; r < 4; ++r) dotc[rt][r] = acc[rt][ct][r];

    #pragma unroll
    for (int ct = 0; ct < 8; ++ct) {
        const float cv = cn2[wv * 128 + ct * 16 + l15];
        #pragma unroll
        for (int rt = 0; rt < 2; ++rt)
            #pragma unroll
            for (int r = 0; r < 4; ++r)
                acc[rt][ct][r] = w * (acc[rt][ct][r] / fmaxf(sqrtf(dv[rt][r] * cv), GEPS)) + bb;
    }
    if (owner) {
        #pragma unroll
        for (int rt = 0; rt < 2; ++rt)
            #pragma unroll
            for (int r = 0; r < 4; ++r) {
                const float d2  = dv[rt][r];
                const float num = (float)NU * dotc[rt][r] - d2;
                const float X   = (float)(NU * NU) * cn2s - 2.0f * NU * dotc[rt][r] + d2;
                const float den = fmaxf(sqrtf(d2) * sqrtf(X), GEPS * (NU - 1));
                const float ls  = w * (num / den) + bb;
                #pragma unroll
                for (int ct = 0; ct < 8; ++ct)
                    if (ct == ctd) acc[rt][ct][r] = ls;
                sSelf[rt * 16 + lg * 4 + r] = ls;
            }
    }
    #pragma unroll
    for (int rt = 0; rt < 2; ++rt) {
        #pragma unroll
        for (int r = 0; r < 4; ++r) {
            float mx = -INFINITY;
            #pragma unroll
            for (int ct = 0; ct < 8; ++ct) mx = fmaxf(mx, acc[rt][ct][r]);
            mx = fmaxf(mx, __shfl_xor(mx, 1)); mx = fmaxf(mx, __shfl_xor(mx, 2));
            mx = fmaxf(mx, __shfl_xor(mx, 4)); mx = fmaxf(mx, __shfl_xor(mx, 8));
            float se = 0.f;
            #pragma unroll
            for (int ct = 0; ct < 8; ++ct) se += expf(acc[rt][ct][r] - mx);
            se += __shfl_xor(se, 1); se += __shfl_xor(se, 2);
            se += __shfl_xor(se, 4); se += __shfl_xor(se, 8);
            if (l15 == 0) {
                sMax[wv][rt * 16 + lg * 4 + r] = mx;
                sSum[wv][rt * 16 + lg * 4 + r] = se;
            }
        }
    }
    __syncthreads();
    if (tid < 32) {
        float M = fmaxf(fmaxf(sMax[0][tid], sMax[1][tid]), fmaxf(sMax[2][tid], sMax[3][tid]));
        float S = sSum[0][tid] * expf(sMax[0][tid] - M) + sSum[1][tid] * expf(sMax[1][tid] - M)
                + sSum[2][tid] * expf(sMax[2][tid] - M) + sSum[3][tid] * expf(sMax[3][tid] - M);
        sRow[tid] = logf(S) + M - sSelf[tid];
    }
    __syncthreads();
    if (tid == 0) {
        float tot = 0.f;
        #pragma unroll
        for (int u2 = 0; u2 < 32; ++u2) tot += sRow[u2];
        atomicAdd(out, tot);
    }
}

extern "C" void kernel_launch(void* const* d_in, const int* in_sizes, int n_in,
                              void* d_out, int out_size, void* d_ws, size_t ws_size,
                              hipStream_t stream) {
    const float* dvecs = (const float*)d_in[0];
    const float* w     = (const float*)d_in[1];
    const float* b     = (const float*)d_in[2];
    float* out = (float*)d_out;

    _Float16* ch  = (_Float16*)d_ws;
    _Float16* cl  = ch + (size_t)NS * ND;
    float*    cn2 = (float*)(cl + (size_t)NS * ND);
    float*    dn2 = cn2 + NS;

    hipMemsetAsync(d_out, 0, sizeof(float), stream);
    prep_kernel<<<NS, 256, 0, stream>>>(dvecs, ch, cl, cn2, dn2);
    ge2e_mfma<<<NS, 256, 0, stream>>>(dvecs, ch, cl, cn2, dn2, w, b, out);
}

// Round 4
// 136.322 us; speedup vs baseline: 1.6744x; 1.1861x over previous
//
#include <hip/hip_runtime.h>
#include <math.h>

#define NS 512
#define NU 32
#define ND 512
#define GEPS 1e-6f

typedef float f4 __attribute__((ext_vector_type(4)));
typedef _Float16 half8 __attribute__((ext_vector_type(8)));

// ws layout: bpk[32*16*1024] _Float16 (1 MiB)  | cn2[NS] f32
// bpk chunk for (ct_g, t): 1024 halves = [hi: (lg*16+l15)*8+j][lo: +512],
// element (lg,l15,j) = centroid[col=ct_g*16+l15][k=t*32+lg*8+j]

__global__ __launch_bounds__(256) void prep_kernel(const float* __restrict__ dvecs,
                                                   _Float16* __restrict__ bpk,
                                                   float* __restrict__ cn2) {
    const int s = blockIdx.x, t = threadIdx.x;
    const float* base = dvecs + (size_t)s * NU * ND;
    const int d0 = t * 2;
    float sx = 0.f, sy = 0.f;
    for (int u = 0; u < NU; ++u) {          // coalesced: wave reads 512B/u
        float2 v = *(const float2*)(base + u * ND + d0);
        sx += v.x; sy += v.y;
    }
    sx *= (1.0f / NU); sy *= (1.0f / NU);

    float c2 = sx * sx + sy * sy;
    #pragma unroll
    for (int m = 1; m < 64; m <<= 1) c2 += __shfl_xor(c2, m);
    __shared__ float red[4];
    if ((t & 63) == 0) red[t >> 6] = c2;
    __syncthreads();
    if (t == 0) cn2[s] = red[0] + red[1] + red[2] + red[3];

    // hi/lo split, packed scatter (this speaker is column s of B)
    _Float16 hx = (_Float16)sx, hy = (_Float16)sy;
    _Float16 lx = (_Float16)(sx - (float)hx), ly = (_Float16)(sy - (float)hy);
    const int ct_g = s >> 4, l15 = s & 15;
    const int tt = d0 >> 5, lg = (d0 >> 3) & 3, j = d0 & 7;   // j even
    size_t hbase = ((size_t)(ct_g * 16 + tt)) * 1024 + (lg * 16 + l15) * 8 + j;
    unsigned hi2 = (unsigned)__builtin_bit_cast(unsigned short, hx)
                 | ((unsigned)__builtin_bit_cast(unsigned short, hy) << 16);
    unsigned lo2 = (unsigned)__builtin_bit_cast(unsigned short, lx)
                 | ((unsigned)__builtin_bit_cast(unsigned short, ly) << 16);
    *(unsigned*)(bpk + hbase)       = hi2;
    *(unsigned*)(bpk + hbase + 512) = lo2;
}

// One block per speaker, 8 waves. Wave wv owns cols [wv*64, wv*64+64) = 4 tiles.
// K=512 in 16 steps. fp32 GEMM via 4-term f16 hi/lo split MFMA.
__global__ __launch_bounds__(512, 4) void ge2e_mfma(const float* __restrict__ dvecs,
                                                    const _Float16* __restrict__ bpk,
                                                    const float* __restrict__ cn2,
                                                    const float* __restrict__ wp,
                                                    const float* __restrict__ bp,
                                                    float* __restrict__ out) {
    const int s = blockIdx.x, tid = threadIdx.x;
    const int l = tid & 63, wv = tid >> 6;
    const int l15 = l & 15, lg = l >> 4;

    f4 acc[2][4];
    #pragma unroll
    for (int rt = 0; rt < 2; ++rt)
        #pragma unroll
        for (int ct = 0; ct < 4; ++ct) acc[rt][ct] = (f4){0.f, 0.f, 0.f, 0.f};
    float dnp[2] = {0.f, 0.f};

    const float*    Ab0 = dvecs + (size_t)s * NU * ND + (size_t)l15 * ND + lg * 8;
    const _Float16* Bb  = bpk + (size_t)(wv * 4) * 16 * 1024 + l * 8;

    for (int t = 0; t < 16; ++t) {
        // B: 4 ct x (hi,lo), each a contiguous 1KiB wave-load
        half8 bh[4], bl[4];
        #pragma unroll
        for (int ct = 0; ct < 4; ++ct) {
            const _Float16* p = Bb + (size_t)(ct * 16 + t) * 1024;
            bh[ct] = *(const half8*)p;
            bl[ct] = *(const half8*)(p + 512);
        }
        // A: fp32 load + on-the-fly hi/lo split (+ exact dn2 accumulation)
        half8 ah[2], al[2];
        #pragma unroll
        for (int rt = 0; rt < 2; ++rt) {
            const float* ap = Ab0 + rt * 16 * ND + t * 32;
            f4 a0 = *(const f4*)ap, a1 = *(const f4*)(ap + 4);
            dnp[rt] += a0[0]*a0[0] + a0[1]*a0[1] + a0[2]*a0[2] + a0[3]*a0[3]
                     + a1[0]*a1[0] + a1[1]*a1[1] + a1[2]*a1[2] + a1[3]*a1[3];
            #pragma unroll
            for (int i = 0; i < 4; ++i) {
                _Float16 h0 = (_Float16)a0[i];
                ah[rt][i]     = h0; al[rt][i]     = (_Float16)(a0[i] - (float)h0);
                _Float16 h1 = (_Float16)a1[i];
                ah[rt][4 + i] = h1; al[rt][4 + i] = (_Float16)(a1[i] - (float)h1);
            }
        }
        #pragma unroll
        for (int ct = 0; ct < 4; ++ct)
            #pragma unroll
            for (int rt = 0; rt < 2; ++rt) {
                acc[rt][ct] = __builtin_amdgcn_mfma_f32_16x16x32_f16(ah[rt], bh[ct], acc[rt][ct], 0, 0, 0);
                acc[rt][ct] = __builtin_amdgcn_mfma_f32_16x16x32_f16(ah[rt], bl[ct], acc[rt][ct], 0, 0, 0);
                acc[rt][ct] = __builtin_amdgcn_mfma_f32_16x16x32_f16(al[rt], bh[ct], acc[rt][ct], 0, 0, 0);
                acc[rt][ct] = __builtin_amdgcn_mfma_f32_16x16x32_f16(al[rt], bl[ct], acc[rt][ct], 0, 0, 0);
            }
    }

    // dn2: reduce squares over the lg group (lanes differing in bits 4,5)
    #pragma unroll
    for (int rt = 0; rt < 2; ++rt) {
        dnp[rt] += __shfl_xor(dnp[rt], 16);
        dnp[rt] += __shfl_xor(dnp[rt], 32);
    }
    __shared__ float sDn2[32], sSelf[32], sMax[8][32], sSum[8][32], sRow[32];
    if (wv == 0 && l < 16) { sDn2[l15] = dnp[0]; sDn2[16 + l15] = dnp[1]; }
    __syncthreads();

    // ---- epilogue. C/D layout: row = rt*16 + lg*4 + r, col = wv*64 + ct*16 + l15
    const float w = wp[0], bb = bp[0];
    const float cn2s = cn2[s];
    float dv[2][4];
    #pragma unroll
    for (int rt = 0; rt < 2; ++rt)
        #pragma unroll
        for (int r = 0; r < 4; ++r) dv[rt][r] = sDn2[rt * 16 + lg * 4 + r];

    const bool owner = (wv == (s >> 6)) && (l15 == (s & 15));
    const int  ctd   = (s >> 4) & 3;

    float dotc[2][4];
    #pragma unroll
    for (int ct = 0; ct < 4; ++ct)
        if (ct == ctd)
            #pragma unroll
            for (int rt = 0; rt < 2; ++rt)
                #pragma unroll
                for (int r = 0; r < 4; ++r) dotc[rt][r] = acc[rt][ct][r];

    #pragma unroll
    for (int ct = 0; ct < 4; ++ct) {
        const float cv = cn2[wv * 64 + ct * 16 + l15];
        #pragma unroll
        for (int rt = 0; rt < 2; ++rt)
            #pragma unroll
            for (int r = 0; r < 4; ++r)
                acc[rt][ct][r] = w * (acc[rt][ct][r] / fmaxf(sqrtf(dv[rt][r] * cv), GEPS)) + bb;
    }
    if (owner) {
        #pragma unroll
        for (int rt = 0; rt < 2; ++rt)
            #pragma unroll
            for (int r = 0; r < 4; ++r) {
                const float d2  = dv[rt][r];
                const float num = (float)NU * dotc[rt][r] - d2;
                const float X   = (float)(NU * NU) * cn2s - 2.0f * NU * dotc[rt][r] + d2;
                const float den = fmaxf(sqrtf(d2) * sqrtf(X), GEPS * (NU - 1));
                const float ls  = w * (num / den) + bb;
                #pragma unroll
                for (int ct = 0; ct < 4; ++ct)
                    if (ct == ctd) acc[rt][ct][r] = ls;
                sSelf[rt * 16 + lg * 4 + r] = ls;
            }
    }

    #pragma unroll
    for (int rt = 0; rt < 2; ++rt)
        #pragma unroll
        for (int r = 0; r < 4; ++r) {
            float mx = -INFINITY;
            #pragma unroll
            for (int ct = 0; ct < 4; ++ct) mx = fmaxf(mx, acc[rt][ct][r]);
            mx = fmaxf(mx, __shfl_xor(mx, 1)); mx = fmaxf(mx, __shfl_xor(mx, 2));
            mx = fmaxf(mx, __shfl_xor(mx, 4)); mx = fmaxf(mx, __shfl_xor(mx, 8));
            float se = 0.f;
            #pragma unroll
            for (int ct = 0; ct < 4; ++ct) se += expf(acc[rt][ct][r] - mx);
            se += __shfl_xor(se, 1); se += __shfl_xor(se, 2);
            se += __shfl_xor(se, 4); se += __shfl_xor(se, 8);
            if (l15 == 0) {
                sMax[wv][rt * 16 + lg * 4 + r] = mx;
                sSum[wv][rt * 16 + lg * 4 + r] = se;
            }
        }
    __syncthreads();

    if (tid < 32) {
        float M = -INFINITY;
        #pragma unroll
        for (int v = 0; v < 8; ++v) M = fmaxf(M, sMax[v][tid]);
        float S = 0.f;
        #pragma unroll
        for (int v = 0; v < 8; ++v) S += sSum[v][tid] * expf(sMax[v][tid] - M);
        sRow[tid] = logf(S) + M - sSelf[tid];
    }
    __syncthreads();
    if (tid == 0) {
        float tot = 0.f;
        #pragma unroll
        for (int u2 = 0; u2 < 32; ++u2) tot += sRow[u2];
        atomicAdd(out, tot);
    }
}

extern "C" void kernel_launch(void* const* d_in, const int* in_sizes, int n_in,
                              void* d_out, int out_size, void* d_ws, size_t ws_size,
                              hipStream_t stream) {
    const float* dvecs = (const float*)d_in[0];
    const float* w     = (const float*)d_in[1];
    const float* b     = (const float*)d_in[2];
    float* out = (float*)d_out;

    _Float16* bpk = (_Float16*)d_ws;                       // 32*16*1024 halves = 1 MiB
    float*    cn2 = (float*)(bpk + (size_t)32 * 16 * 1024);

    hipMemsetAsync(d_out, 0, sizeof(float), stream);
    prep_kernel<<<NS, 256, 0, stream>>>(dvecs, bpk, cn2);
    ge2e_mfma<<<NS, 512, 0, stream>>>(dvecs, bpk, cn2, w, b, out);
}

// Round 8
// 128.421 us; speedup vs baseline: 1.7774x; 1.0615x over previous
//
#include <hip/hip_runtime.h>
#include <math.h>

#define NS 512
#define NU 32
#define ND 512
#define GEPS 1e-6f

typedef float f4 __attribute__((ext_vector_type(4)));
typedef _Float16 half8 __attribute__((ext_vector_type(8)));

// ---------------- full path (needs ~34.7 MB ws) ----------------
// bpk chunk (ct_g, t): 1024 halves [hi 512 | lo 512], elem l*8+j = cent[col=ct_g*16+(l&15)][k=t*32+(l>>4)*8+j]
// apk chunk (s, rt, t): 1024 halves [hi 512 | lo 512], elem l*8+j = dvec[s][row=rt*16+(l&15)][k=t*32+(l>>4)*8+j]

__global__ __launch_bounds__(256) void prep_full(const float* __restrict__ dvecs,
                                                 _Float16* __restrict__ bpk,
                                                 float* __restrict__ cn2,
                                                 float* __restrict__ dn2,
                                                 _Float16* __restrict__ apk) {
    const int s = blockIdx.x, t = threadIdx.x;
    const int l = t & 63, wv = t >> 6, l15 = l & 15, lg = l >> 4;
    const float* base = dvecs + (size_t)s * NU * ND;
    __shared__ float red[4];

    // phase 1: coalesced centroid accumulation over u (streams 64KB thru L1/L2)
    const int d0 = t * 2;
    float sx = 0.f, sy = 0.f;
    #pragma unroll 4
    for (int u = 0; u < NU; ++u) {
        float2 v = *(const float2*)(base + u * ND + d0);
        sx += v.x; sy += v.y;
    }
    sx *= (1.0f / NU); sy *= (1.0f / NU);
    float c2 = sx * sx + sy * sy;
    #pragma unroll
    for (int m = 1; m < 64; m <<= 1) c2 += __shfl_xor(c2, m);
    if ((t & 63) == 0) red[t >> 6] = c2;

    // bpk scatter (speaker s is column s of B)
    {
        _Float16 hx = (_Float16)sx, hy = (_Float16)sy;
        _Float16 lx = (_Float16)(sx - (float)hx), ly = (_Float16)(sy - (float)hy);
        const int ct_g = s >> 4, cl15 = s & 15;
        const int tt = d0 >> 5, blg = (d0 >> 3) & 3, j = d0 & 7;   // j even
        size_t hbase = ((size_t)(ct_g * 16 + tt)) * 1024 + (blg * 16 + cl15) * 8 + j;
        unsigned hi2 = (unsigned)__builtin_bit_cast(unsigned short, hx)
                     | ((unsigned)__builtin_bit_cast(unsigned short, hy) << 16);
        unsigned lo2 = (unsigned)__builtin_bit_cast(unsigned short, lx)
                     | ((unsigned)__builtin_bit_cast(unsigned short, ly) << 16);
        *(unsigned*)(bpk + hbase)       = hi2;
        *(unsigned*)(bpk + hbase + 512) = lo2;
    }
    __syncthreads();
    if (t == 0) cn2[s] = red[0] + red[1] + red[2] + red[3];

    // phase 2: exact fp32 dn2[u]; 8 threads per u, each 8-lane group eats whole
    // 128B lines (L2-hot after phase 1)
    {
        const int u = t >> 3, jj = t & 7;
        const float* up = base + u * ND + jj * 4;
        float q = 0.f;
        #pragma unroll
        for (int i = 0; i < 16; ++i) {
            f4 v = *(const f4*)(up + i * 32);
            q += v[0]*v[0] + v[1]*v[1] + v[2]*v[2] + v[3]*v[3];
        }
        q += __shfl_xor(q, 1); q += __shfl_xor(q, 2); q += __shfl_xor(q, 4);
        if (jj == 0) dn2[s * NU + u] = q;
    }

    // phase 3: A hi/lo split -> packed fragment chunks. Read: 4 lanes of equal
    // l15 cover one contiguous 128B row segment (16 full lines per load, L2-hot).
    // Write: contiguous 1KiB per chunk.
    #pragma unroll
    for (int i = 0; i < 8; ++i) {
        const int idx = wv * 8 + i;          // 32 chunks = rt*16 + tk
        const int rt = idx >> 4, tk = idx & 15;
        const int u = rt * 16 + l15, k = tk * 32 + lg * 8;
        const float* ap = base + (size_t)u * ND + k;
        f4 a0 = *(const f4*)ap;
        f4 a1 = *(const f4*)(ap + 4);
        half8 h, lo;
        #pragma unroll
        for (int i2 = 0; i2 < 4; ++i2) {
            _Float16 h0 = (_Float16)a0[i2];
            h[i2]     = h0; lo[i2]     = (_Float16)(a0[i2] - (float)h0);
            _Float16 h1 = (_Float16)a1[i2];
            h[4 + i2] = h1; lo[4 + i2] = (_Float16)(a1[i2] - (float)h1);
        }
        _Float16* cb = apk + ((size_t)(s * 2 + rt) * 16 + tk) * 1024 + l * 8;
        *(half8*)cb         = h;
        *(half8*)(cb + 512) = lo;
    }
}

__global__ __launch_bounds__(512, 4) void ge2e_full(const _Float16* __restrict__ apk,
                                                    const _Float16* __restrict__ bpk,
                                                    const float* __restrict__ cn2,
                                                    const float* __restrict__ dn2,
                                                    const float* __restrict__ wp,
                                                    const float* __restrict__ bp,
                                                    float* __restrict__ out) {
    const int s = blockIdx.x, tid = threadIdx.x;
    const int l = tid & 63, wv = tid >> 6;
    const int l15 = l & 15, lg = l >> 4;

    f4 acc[2][4];
    #pragma unroll
    for (int rt = 0; rt < 2; ++rt)
        #pragma unroll
        for (int ct = 0; ct < 4; ++ct) acc[rt][ct] = (f4){0.f, 0.f, 0.f, 0.f};

    const _Float16* Ab = apk + (size_t)s * 32 * 1024 + l * 8;
    const _Float16* Bb = bpk + (size_t)(wv * 4) * 16 * 1024 + l * 8;

    for (int t = 0; t < 16; ++t) {
        half8 bh[4], bl[4], ah[2], al[2];
        #pragma unroll
        for (int ct = 0; ct < 4; ++ct) {
            const _Float16* p = Bb + (size_t)(ct * 16 + t) * 1024;
            bh[ct] = *(const half8*)p;
            bl[ct] = *(const half8*)(p + 512);
        }
        #pragma unroll
        for (int rt = 0; rt < 2; ++rt) {
            const _Float16* p = Ab + (size_t)(rt * 16 + t) * 1024;
            ah[rt] = *(const half8*)p;
            al[rt] = *(const half8*)(p + 512);
        }
        #pragma unroll
        for (int ct = 0; ct < 4; ++ct)
            #pragma unroll
            for (int rt = 0; rt < 2; ++rt) {
                acc[rt][ct] = __builtin_amdgcn_mfma_f32_16x16x32_f16(ah[rt], bh[ct], acc[rt][ct], 0, 0, 0);
                acc[rt][ct] = __builtin_amdgcn_mfma_f32_16x16x32_f16(ah[rt], bl[ct], acc[rt][ct], 0, 0, 0);
                acc[rt][ct] = __builtin_amdgcn_mfma_f32_16x16x32_f16(al[rt], bh[ct], acc[rt][ct], 0, 0, 0);
                acc[rt][ct] = __builtin_amdgcn_mfma_f32_16x16x32_f16(al[rt], bl[ct], acc[rt][ct], 0, 0, 0);
            }
    }

    __shared__ float sDn2[32], sSelf[32], sMax[8][32], sSum[8][32], sRow[32];
    if (tid < 32) sDn2[tid] = dn2[s * NU + tid];
    __syncthreads();

    const float w = wp[0], bb = bp[0];
    const float cn2s = cn2[s];
    float dv[2][4];
    #pragma unroll
    for (int rt = 0; rt < 2; ++rt)
        #pragma unroll
        for (int r = 0; r < 4; ++r) dv[rt][r] = sDn2[rt * 16 + lg * 4 + r];

    const bool owner = (wv == (s >> 6)) && (l15 == (s & 15));
    const int  ctd   = (s >> 4) & 3;

    float dotc[2][4];
    #pragma unroll
    for (int ct = 0; ct < 4; ++ct)
        if (ct == ctd)
            #pragma unroll
            for (int rt = 0; rt < 2; ++rt)
                #pragma unroll
                for (int r = 0; r < 4; ++r) dotc[rt][r] = acc[rt][ct][r];

    #pragma unroll
    for (int ct = 0; ct < 4; ++ct) {
        const float cv = cn2[wv * 64 + ct * 16 + l15];
        #pragma unroll
        for (int rt = 0; rt < 2; ++rt)
            #pragma unroll
            for (int r = 0; r < 4; ++r)
                acc[rt][ct][r] = w * (acc[rt][ct][r] / fmaxf(sqrtf(dv[rt][r] * cv), GEPS)) + bb;
    }
    if (owner) {
        #pragma unroll
        for (int rt = 0; rt < 2; ++rt)
            #pragma unroll
            for (int r = 0; r < 4; ++r) {
                const float d2  = dv[rt][r];
                const float num = (float)NU * dotc[rt][r] - d2;
                const float X   = (float)(NU * NU) * cn2s - 2.0f * NU * dotc[rt][r] + d2;
                const float den = fmaxf(sqrtf(d2) * sqrtf(X), GEPS * (NU - 1));
                const float ls  = w * (num / den) + bb;
                #pragma unroll
                for (int ct = 0; ct < 4; ++ct)
                    if (ct == ctd) acc[rt][ct][r] = ls;
                sSelf[rt * 16 + lg * 4 + r] = ls;
            }
    }

    #pragma unroll
    for (int rt = 0; rt < 2; ++rt)
        #pragma unroll
        for (int r = 0; r < 4; ++r) {
            float mx = -INFINITY;
            #pragma unroll
            for (int ct = 0; ct < 4; ++ct) mx = fmaxf(mx, acc[rt][ct][r]);
            mx = fmaxf(mx, __shfl_xor(mx, 1)); mx = fmaxf(mx, __shfl_xor(mx, 2));
            mx = fmaxf(mx, __shfl_xor(mx, 4)); mx = fmaxf(mx, __shfl_xor(mx, 8));
            float se = 0.f;
            #pragma unroll
            for (int ct = 0; ct < 4; ++ct) se += expf(acc[rt][ct][r] - mx);
            se += __shfl_xor(se, 1); se += __shfl_xor(se, 2);
            se += __shfl_xor(se, 4); se += __shfl_xor(se, 8);
            if (l15 == 0) {
                sMax[wv][rt * 16 + lg * 4 + r] = mx;
                sSum[wv][rt * 16 + lg * 4 + r] = se;
            }
        }
    __syncthreads();

    if (tid < 32) {
        float M = -INFINITY;
        #pragma unroll
        for (int v = 0; v < 8; ++v) M = fmaxf(M, sMax[v][tid]);
        float S = 0.f;
        #pragma unroll
        for (int v = 0; v < 8; ++v) S += sSum[v][tid] * expf(sMax[v][tid] - M);
        sRow[tid] = logf(S) + M - sSelf[tid];
    }
    __syncthreads();
    if (tid == 0) {
        float tot = 0.f;
        #pragma unroll
        for (int u2 = 0; u2 < 32; ++u2) tot += sRow[u2];
        atomicAdd(out, tot);
    }
}

// ---------------- fallback path (R4, needs ~1.05 MB ws) ----------------

__global__ __launch_bounds__(256) void prep_fb(const float* __restrict__ dvecs,
                                               _Float16* __restrict__ bpk,
                                               float* __restrict__ cn2) {
    const int s = blockIdx.x, t = threadIdx.x;
    const float* base = dvecs + (size_t)s * NU * ND;
    const int d0 = t * 2;
    float sx = 0.f, sy = 0.f;
    for (int u = 0; u < NU; ++u) {
        float2 v = *(const float2*)(base + u * ND + d0);
        sx += v.x; sy += v.y;
    }
    sx *= (1.0f / NU); sy *= (1.0f / NU);
    float c2 = sx * sx + sy * sy;
    #pragma unroll
    for (int m = 1; m < 64; m <<= 1) c2 += __shfl_xor(c2, m);
    __shared__ float red[4];
    if ((t & 63) == 0) red[t >> 6] = c2;
    __syncthreads();
    if (t == 0) cn2[s] = red[0] + red[1] + red[2] + red[3];
    _Float16 hx = (_Float16)sx, hy = (_Float16)sy;
    _Float16 lx = (_Float16)(sx - (float)hx), ly = (_Float16)(sy - (float)hy);
    const int ct_g = s >> 4, l15 = s & 15;
    const int tt = d0 >> 5, lg = (d0 >> 3) & 3, j = d0 & 7;
    size_t hbase = ((size_t)(ct_g * 16 + tt)) * 1024 + (lg * 16 + l15) * 8 + j;
    unsigned hi2 = (unsigned)__builtin_bit_cast(unsigned short, hx)
                 | ((unsigned)__builtin_bit_cast(unsigned short, hy) << 16);
    unsigned lo2 = (unsigned)__builtin_bit_cast(unsigned short, lx)
                 | ((unsigned)__builtin_bit_cast(unsigned short, ly) << 16);
    *(unsigned*)(bpk + hbase)       = hi2;
    *(unsigned*)(bpk + hbase + 512) = lo2;
}

__global__ __launch_bounds__(512, 4) void ge2e_fb(const float* __restrict__ dvecs,
                                                  const _Float16* __restrict__ bpk,
                                                  const float* __restrict__ cn2,
                                                  const float* __restrict__ wp,
                                                  const float* __restrict__ bp,
                                                  float* __restrict__ out) {
    const int s = blockIdx.x, tid = threadIdx.x;
    const int l = tid & 63, wv = tid >> 6;
    const int l15 = l & 15, lg = l >> 4;
    f4 acc[2][4];
    #pragma unroll
    for (int rt = 0; rt < 2; ++rt)
        #pragma unroll
        for (int ct = 0; ct < 4; ++ct) acc[rt][ct] = (f4){0.f, 0.f, 0.f, 0.f};
    float dnp[2] = {0.f, 0.f};
    const float*    Ab0 = dvecs + (size_t)s * NU * ND + (size_t)l15 * ND + lg * 8;
    const _Float16* Bb  = bpk + (size_t)(wv * 4) * 16 * 1024 + l * 8;
    for (int t = 0; t < 16; ++t) {
        half8 bh[4], bl[4];
        #pragma unroll
        for (int ct = 0; ct < 4; ++ct) {
            const _Float16* p = Bb + (size_t)(ct * 16 + t) * 1024;
            bh[ct] = *(const half8*)p;
            bl[ct] = *(const half8*)(p + 512);
        }
        half8 ah[2], al[2];
        #pragma unroll
        for (int rt = 0; rt < 2; ++rt) {
            const float* ap = Ab0 + rt * 16 * ND + t * 32;
            f4 a0 = *(const f4*)ap, a1 = *(const f4*)(ap + 4);
            dnp[rt] += a0[0]*a0[0] + a0[1]*a0[1] + a0[2]*a0[2] + a0[3]*a0[3]
                     + a1[0]*a1[0] + a1[1]*a1[1] + a1[2]*a1[2] + a1[3]*a1[3];
            #pragma unroll
            for (int i = 0; i < 4; ++i) {
                _Float16 h0 = (_Float16)a0[i];
                ah[rt][i]     = h0; al[rt][i]     = (_Float16)(a0[i] - (float)h0);
                _Float16 h1 = (_Float16)a1[i];
                ah[rt][4 + i] = h1; al[rt][4 + i] = (_Float16)(a1[i] - (float)h1);
            }
        }
        #pragma unroll
        for (int ct = 0; ct < 4; ++ct)
            #pragma unroll
            for (int rt = 0; rt < 2; ++rt) {
                acc[rt][ct] = __builtin_amdgcn_mfma_f32_16x16x32_f16(ah[rt], bh[ct], acc[rt][ct], 0, 0, 0);
                acc[rt][ct] = __builtin_amdgcn_mfma_f32_16x16x32_f16(ah[rt], bl[ct], acc[rt][ct], 0, 0, 0);
                acc[rt][ct] = __builtin_amdgcn_mfma_f32_16x16x32_f16(al[rt], bh[ct], acc[rt][ct], 0, 0, 0);
                acc[rt][ct] = __builtin_amdgcn_mfma_f32_16x16x32_f16(al[rt], bl[ct], acc[rt][ct], 0, 0, 0);
            }
    }
    #pragma unroll
    for (int rt = 0; rt < 2; ++rt) {
        dnp[rt] += __shfl_xor(dnp[rt], 16);
        dnp[rt] += __shfl_xor(dnp[rt], 32);
    }
    __shared__ float sDn2[32], sSelf[32], sMax[8][32], sSum[8][32], sRow[32];
    if (wv == 0 && l < 16) { sDn2[l15] = dnp[0]; sDn2[16 + l15] = dnp[1]; }
    __syncthreads();
    const float w = wp[0], bb = bp[0];
    const float cn2s = cn2[s];
    float dv[2][4];
    #pragma unroll
    for (int rt = 0; rt < 2; ++rt)
        #pragma unroll
        for (int r = 0; r < 4; ++r) dv[rt][r] = sDn2[rt * 16 + lg * 4 + r];
    const bool owner = (wv == (s >> 6)) && (l15 == (s & 15));
    const int  ctd   = (s >> 4) & 3;
    float dotc[2][4];
    #pragma unroll
    for (int ct = 0; ct < 4; ++ct)
        if (ct == ctd)
            #pragma unroll
            for (int rt = 0; rt < 2; ++rt)
                #pragma unroll
                for (int r = 0; r < 4; ++r) dotc[rt][r] = acc[rt][ct][r];
    #pragma unroll
    for (int ct = 0; ct < 4; ++ct) {
        const float cv = cn2[wv * 64 + ct * 16 + l15];
        #pragma unroll
        for (int rt = 0; rt < 2; ++rt)
            #pragma unroll
            for (int r = 0; r < 4; ++r)
                acc[rt][ct][r] = w * (acc[rt][ct][r] / fmaxf(sqrtf(dv[rt][r] * cv), GEPS)) + bb;
    }
    if (owner) {
        #pragma unroll
        for (int rt = 0; rt < 2; ++rt)
            #pragma unroll
            for (int r = 0; r < 4; ++r) {
                const float d2  = dv[rt][r];
                const float num = (float)NU * dotc[rt][r] - d2;
                const float X   = (float)(NU * NU) * cn2s - 2.0f * NU * dotc[rt][r] + d2;
                const float den = fmaxf(sqrtf(d2) * sqrtf(X), GEPS * (NU - 1));
                const float ls  = w * (num / den) + bb;
                #pragma unroll
                for (int ct = 0; ct < 4; ++ct)
                    if (ct == ctd) acc[rt][ct][r] = ls;
                sSelf[rt * 16 + lg * 4 + r] = ls;
            }
    }
    #pragma unroll
    for (int rt = 0; rt < 2; ++rt)
        #pragma unroll
        for (int r = 0; r < 4; ++r) {
            float mx = -INFINITY;
            #pragma unroll
            for (int ct = 0; ct < 4; ++ct) mx = fmaxf(mx, acc[rt][ct][r]);
            mx = fmaxf(mx, __shfl_xor(mx, 1)); mx = fmaxf(mx, __shfl_xor(mx, 2));
            mx = fmaxf(mx, __shfl_xor(mx, 4)); mx = fmaxf(mx, __shfl_xor(mx, 8));
            float se = 0.f;
            #pragma unroll
            for (int ct = 0; ct < 4; ++ct) se += expf(acc[rt][ct][r] - mx);
            se += __shfl_xor(se, 1); se += __shfl_xor(se, 2);
            se += __shfl_xor(se, 4); se += __shfl_xor(se, 8);
            if (l15 == 0) {
                sMax[wv][rt * 16 + lg * 4 + r] = mx;
                sSum[wv][rt * 16 + lg * 4 + r] = se;
            }
        }
    __syncthreads();
    if (tid < 32) {
        float M = -INFINITY;
        #pragma unroll
        for (int v = 0; v < 8; ++v) M = fmaxf(M, sMax[v][tid]);
        float S = 0.f;
        #pragma unroll
        for (int v = 0; v < 8; ++v) S += sSum[v][tid] * expf(sMax[v][tid] - M);
        sRow[tid] = logf(S) + M - sSelf[tid];
    }
    __syncthreads();
    if (tid == 0) {
        float tot = 0.f;
        #pragma unroll
        for (int u2 = 0; u2 < 32; ++u2) tot += sRow[u2];
        atomicAdd(out, tot);
    }
}

extern "C" void kernel_launch(void* const* d_in, const int* in_sizes, int n_in,
                              void* d_out, int out_size, void* d_ws, size_t ws_size,
                              hipStream_t stream) {
    const float* dvecs = (const float*)d_in[0];
    const float* w     = (const float*)d_in[1];
    const float* b     = (const float*)d_in[2];
    float* out = (float*)d_out;

    const size_t bpk_b = (size_t)32 * 16 * 1024 * sizeof(_Float16);     // 1 MiB
    const size_t cn2_b = (size_t)NS * sizeof(float);
    const size_t dn2_b = (size_t)NS * NU * sizeof(float);
    const size_t apk_b = (size_t)NS * 2 * 16 * 1024 * sizeof(_Float16); // 33.5 MiB
    const size_t need  = bpk_b + cn2_b + dn2_b + apk_b;

    char* p = (char*)d_ws;
    _Float16* bpk = (_Float16*)p;                 p += bpk_b;
    float*    cn2 = (float*)p;                    p += cn2_b;
    float*    dn2 = (float*)p;                    p += dn2_b;
    _Float16* apk = (_Float16*)p;

    hipMemsetAsync(d_out, 0, sizeof(float), stream);
    if (ws_size >= need) {
        prep_full<<<NS, 256, 0, stream>>>(dvecs, bpk, cn2, dn2, apk);
        ge2e_full<<<NS, 512, 0, stream>>>(apk, bpk, cn2, dn2, w, b, out);
    } else {
        prep_fb<<<NS, 256, 0, stream>>>(dvecs, bpk, cn2);
        ge2e_fb<<<NS, 512, 0, stream>>>(dvecs, bpk, cn2, w, b, out);
    }
}

// Round 9
// 126.695 us; speedup vs baseline: 1.8016x; 1.0136x over previous
//
#include <hip/hip_runtime.h>
#include <math.h>

#define NS 512
#define NU 32
#define ND 512
#define GEPS 1e-6f

typedef float f4 __attribute__((ext_vector_type(4)));
typedef _Float16 half8 __attribute__((ext_vector_type(8)));

// ---------------- full path (needs ~34.7 MB ws) ----------------
// bpk chunk (ct_g, t): 1024 halves [hi 512 | lo 512], elem l*8+j = cent[col=ct_g*16+(l&15)][k=t*32+(l>>4)*8+j]
// apk chunk (s, rt, t): 1024 halves [hi 512 | lo 512], elem l*8+j = dvec[s][row=rt*16+(l&15)][k=t*32+(l>>4)*8+j]

// prep v3: single global pass. 4 waves; wave w owns (rt=w>>1, tk half) -> 8 chunks.
// Lane reads its own fragment (16 rows x 128B lines, fully coalesced), converts,
// stores apk coalesced; dn2 accumulates in-register; centroid via 16-row shfl.
__global__ __launch_bounds__(256) void prep_full(const float* __restrict__ dvecs,
                                                 _Float16* __restrict__ bpk,
                                                 float* __restrict__ cn2,
                                                 float* __restrict__ dn2,
                                                 _Float16* __restrict__ apk) {
    const int s = blockIdx.x, t = threadIdx.x;
    const int l = t & 63, w = t >> 6, l15 = l & 15, lg = l >> 4;
    const int rt = w >> 1, tkh = (w & 1) * 8;
    const float* base = dvecs + (size_t)s * NU * ND;

    __shared__ float centp[2][512];
    __shared__ float dn2p[4][16];
    __shared__ float red[4];

    const int u = rt * 16 + l15;
    const float* rowp = base + (size_t)u * ND;
    float q = 0.f;

    #pragma unroll
    for (int i = 0; i < 8; ++i) {
        const int tk = tkh + i;
        const int k0 = tk * 32 + lg * 8;
        f4 a0 = *(const f4*)(rowp + k0);
        f4 a1 = *(const f4*)(rowp + k0 + 4);
        q += a0[0]*a0[0] + a0[1]*a0[1] + a0[2]*a0[2] + a0[3]*a0[3]
           + a1[0]*a1[0] + a1[1]*a1[1] + a1[2]*a1[2] + a1[3]*a1[3];
        half8 h, lo;
        #pragma unroll
        for (int c = 0; c < 4; ++c) {
            _Float16 h0 = (_Float16)a0[c];
            h[c]     = h0; lo[c]     = (_Float16)(a0[c] - (float)h0);
            _Float16 h1 = (_Float16)a1[c];
            h[4 + c] = h1; lo[4 + c] = (_Float16)(a1[c] - (float)h1);
        }
        _Float16* cb = apk + ((size_t)(s * 2 + rt) * 16 + tk) * 1024 + l * 8;
        *(half8*)cb         = h;
        *(half8*)(cb + 512) = lo;
        // centroid partial: sum over the 16 rows (l15 group) of this rt
        f4 s0 = a0, s1 = a1;
        #pragma unroll
        for (int m = 1; m <= 8; m <<= 1) {
            #pragma unroll
            for (int c = 0; c < 4; ++c) {
                s0[c] += __shfl_xor(s0[c], m);
                s1[c] += __shfl_xor(s1[c], m);
            }
        }
        if (l15 == 0) {
            *(f4*)&centp[rt][k0]     = s0;
            *(f4*)&centp[rt][k0 + 4] = s1;
        }
    }
    // dn2: combine lg-group partials (row u fixed per lane)
    q += __shfl_xor(q, 16);
    q += __shfl_xor(q, 32);
    if (lg == 0) dn2p[w][l15] = q;
    __syncthreads();

    if (t < 32)
        dn2[s * NU + t] = dn2p[(t >> 4) * 2][t & 15] + dn2p[(t >> 4) * 2 + 1][t & 15];

    // centroid tail: thread owns d0=t*2, d0+1 (identical downstream to verified code)
    const int d0 = t * 2;
    float cx = (centp[0][d0]     + centp[1][d0])     * (1.0f / NU);
    float cy = (centp[0][d0 + 1] + centp[1][d0 + 1]) * (1.0f / NU);
    float c2 = cx * cx + cy * cy;
    #pragma unroll
    for (int m = 1; m < 64; m <<= 1) c2 += __shfl_xor(c2, m);
    if ((t & 63) == 0) red[t >> 6] = c2;
    __syncthreads();
    if (t == 0) cn2[s] = red[0] + red[1] + red[2] + red[3];

    // bpk scatter (byte-identical layout to the verified R4 path)
    _Float16 hx = (_Float16)cx, hy = (_Float16)cy;
    _Float16 lx = (_Float16)(cx - (float)hx), ly = (_Float16)(cy - (float)hy);
    const int ct_g = s >> 4, cl15 = s & 15;
    const int tt = d0 >> 5, blg = (d0 >> 3) & 3, j = d0 & 7;   // j even
    size_t hbase = ((size_t)(ct_g * 16 + tt)) * 1024 + (blg * 16 + cl15) * 8 + j;
    unsigned hi2 = (unsigned)__builtin_bit_cast(unsigned short, hx)
                 | ((unsigned)__builtin_bit_cast(unsigned short, hy) << 16);
    unsigned lo2 = (unsigned)__builtin_bit_cast(unsigned short, lx)
                 | ((unsigned)__builtin_bit_cast(unsigned short, ly) << 16);
    *(unsigned*)(bpk + hbase)       = hi2;
    *(unsigned*)(bpk + hbase + 512) = lo2;
}

// ge2e v3: SGPR-uniform base pointers (readfirstlane) + fully unrolled K-loop
// (compiler software-pipelines loads under MFMAs) + setprio around MFMA cluster.
__global__ __launch_bounds__(512, 4) void ge2e_full(const _Float16* __restrict__ apk,
                                                    const _Float16* __restrict__ bpk,
                                                    const float* __restrict__ cn2,
                                                    const float* __restrict__ dn2,
                                                    const float* __restrict__ wp,
                                                    const float* __restrict__ bp,
                                                    float* __restrict__ out) {
    const int s = blockIdx.x, tid = threadIdx.x;
    const int l = tid & 63;
    const int wv = __builtin_amdgcn_readfirstlane(tid >> 6);   // wave-uniform -> SGPR
    const int l15 = l & 15, lg = l >> 4;

    f4 acc[2][4];
    #pragma unroll
    for (int rt = 0; rt < 2; ++rt)
        #pragma unroll
        for (int ct = 0; ct < 4; ++ct) acc[rt][ct] = (f4){0.f, 0.f, 0.f, 0.f};

    const _Float16* Au = apk + (size_t)s * 32 * 1024;          // uniform base
    const _Float16* Bu = bpk + (size_t)(wv * 4) * 16 * 1024;   // uniform base
    const int voff = l * 8;                                    // only per-lane term

    #pragma unroll
    for (int t = 0; t < 16; ++t) {
        half8 ah[2], al[2], bh[4], bl[4];
        #pragma unroll
        for (int rt = 0; rt < 2; ++rt) {
            const _Float16* p = Au + (rt * 16 + t) * 1024 + voff;
            ah[rt] = *(const half8*)p;
            al[rt] = *(const half8*)(p + 512);
        }
        #pragma unroll
        for (int ct = 0; ct < 4; ++ct) {
            const _Float16* p = Bu + (ct * 16 + t) * 1024 + voff;
            bh[ct] = *(const half8*)p;
            bl[ct] = *(const half8*)(p + 512);
        }
        __builtin_amdgcn_s_setprio(1);
        #pragma unroll
        for (int ct = 0; ct < 4; ++ct)
            #pragma unroll
            for (int rt = 0; rt < 2; ++rt) {
                acc[rt][ct] = __builtin_amdgcn_mfma_f32_16x16x32_f16(ah[rt], bh[ct], acc[rt][ct], 0, 0, 0);
                acc[rt][ct] = __builtin_amdgcn_mfma_f32_16x16x32_f16(ah[rt], bl[ct], acc[rt][ct], 0, 0, 0);
                acc[rt][ct] = __builtin_amdgcn_mfma_f32_16x16x32_f16(al[rt], bh[ct], acc[rt][ct], 0, 0, 0);
                acc[rt][ct] = __builtin_amdgcn_mfma_f32_16x16x32_f16(al[rt], bl[ct], acc[rt][ct], 0, 0, 0);
            }
        __builtin_amdgcn_s_setprio(0);
    }

    __shared__ float sDn2[32], sSelf[32], sMax[8][32], sSum[8][32], sRow[32];
    if (tid < 32) sDn2[tid] = dn2[s * NU + tid];
    __syncthreads();

    const float w = wp[0], bb = bp[0];
    const float cn2s = cn2[s];
    float dv[2][4];
    #pragma unroll
    for (int rt = 0; rt < 2; ++rt)
        #pragma unroll
        for (int r = 0; r < 4; ++r) dv[rt][r] = sDn2[rt * 16 + lg * 4 + r];

    const bool owner = (wv == (s >> 6)) && (l15 == (s & 15));
    const int  ctd   = (s >> 4) & 3;

    float dotc[2][4];
    #pragma unroll
    for (int ct = 0; ct < 4; ++ct)
        if (ct == ctd)
            #pragma unroll
            for (int rt = 0; rt < 2; ++rt)
                #pragma unroll
                for (int r = 0; r < 4; ++r) dotc[rt][r] = acc[rt][ct][r];

    #pragma unroll
    for (int ct = 0; ct < 4; ++ct) {
        const float cv = cn2[wv * 64 + ct * 16 + l15];
        #pragma unroll
        for (int rt = 0; rt < 2; ++rt)
            #pragma unroll
            for (int r = 0; r < 4; ++r)
                acc[rt][ct][r] = w * (acc[rt][ct][r] / fmaxf(sqrtf(dv[rt][r] * cv), GEPS)) + bb;
    }
    if (owner) {
        #pragma unroll
        for (int rt = 0; rt < 2; ++rt)
            #pragma unroll
            for (int r = 0; r < 4; ++r) {
                const float d2  = dv[rt][r];
                const float num = (float)NU * dotc[rt][r] - d2;
                const float X   = (float)(NU * NU) * cn2s - 2.0f * NU * dotc[rt][r] + d2;
                const float den = fmaxf(sqrtf(d2) * sqrtf(X), GEPS * (NU - 1));
                const float ls  = w * (num / den) + bb;
                #pragma unroll
                for (int ct = 0; ct < 4; ++ct)
                    if (ct == ctd) acc[rt][ct][r] = ls;
                sSelf[rt * 16 + lg * 4 + r] = ls;
            }
    }

    #pragma unroll
    for (int rt = 0; rt < 2; ++rt)
        #pragma unroll
        for (int r = 0; r < 4; ++r) {
            float mx = -INFINITY;
            #pragma unroll
            for (int ct = 0; ct < 4; ++ct) mx = fmaxf(mx, acc[rt][ct][r]);
            mx = fmaxf(mx, __shfl_xor(mx, 1)); mx = fmaxf(mx, __shfl_xor(mx, 2));
            mx = fmaxf(mx, __shfl_xor(mx, 4)); mx = fmaxf(mx, __shfl_xor(mx, 8));
            float se = 0.f;
            #pragma unroll
            for (int ct = 0; ct < 4; ++ct) se += expf(acc[rt][ct][r] - mx);
            se += __shfl_xor(se, 1); se += __shfl_xor(se, 2);
            se += __shfl_xor(se, 4); se += __shfl_xor(se, 8);
            if (l15 == 0) {
                sMax[wv][rt * 16 + lg * 4 + r] = mx;
                sSum[wv][rt * 16 + lg * 4 + r] = se;
            }
        }
    __syncthreads();

    if (tid < 32) {
        float M = -INFINITY;
        #pragma unroll
        for (int v = 0; v < 8; ++v) M = fmaxf(M, sMax[v][tid]);
        float S = 0.f;
        #pragma unroll
        for (int v = 0; v < 8; ++v) S += sSum[v][tid] * expf(sMax[v][tid] - M);
        sRow[tid] = logf(S) + M - sSelf[tid];
    }
    __syncthreads();
    if (tid == 0) {
        float tot = 0.f;
        #pragma unroll
        for (int u2 = 0; u2 < 32; ++u2) tot += sRow[u2];
        atomicAdd(out, tot);
    }
}

// ---------------- fallback path (R4, needs ~1.05 MB ws) ----------------

__global__ __launch_bounds__(256) void prep_fb(const float* __restrict__ dvecs,
                                               _Float16* __restrict__ bpk,
                                               float* __restrict__ cn2) {
    const int s = blockIdx.x, t = threadIdx.x;
    const float* base = dvecs + (size_t)s * NU * ND;
    const int d0 = t * 2;
    float sx = 0.f, sy = 0.f;
    for (int u = 0; u < NU; ++u) {
        float2 v = *(const float2*)(base + u * ND + d0);
        sx += v.x; sy += v.y;
    }
    sx *= (1.0f / NU); sy *= (1.0f / NU);
    float c2 = sx * sx + sy * sy;
    #pragma unroll
    for (int m = 1; m < 64; m <<= 1) c2 += __shfl_xor(c2, m);
    __shared__ float red[4];
    if ((t & 63) == 0) red[t >> 6] = c2;
    __syncthreads();
    if (t == 0) cn2[s] = red[0] + red[1] + red[2] + red[3];
    _Float16 hx = (_Float16)sx, hy = (_Float16)sy;
    _Float16 lx = (_Float16)(sx - (float)hx), ly = (_Float16)(sy - (float)hy);
    const int ct_g = s >> 4, l15 = s & 15;
    const int tt = d0 >> 5, lg = (d0 >> 3) & 3, j = d0 & 7;
    size_t hbase = ((size_t)(ct_g * 16 + tt)) * 1024 + (lg * 16 + l15) * 8 + j;
    unsigned hi2 = (unsigned)__builtin_bit_cast(unsigned short, hx)
                 | ((unsigned)__builtin_bit_cast(unsigned short, hy) << 16);
    unsigned lo2 = (unsigned)__builtin_bit_cast(unsigned short, lx)
                 | ((unsigned)__builtin_bit_cast(unsigned short, ly) << 16);
    *(unsigned*)(bpk + hbase)       = hi2;
    *(unsigned*)(bpk + hbase + 512) = lo2;
}

__global__ __launch_bounds__(512, 4) void ge2e_fb(const float* __restrict__ dvecs,
                                                  const _Float16* __restrict__ bpk,
                                                  const float* __restrict__ cn2,
                                                  const float* __restrict__ wp,
                                                  const float* __restrict__ bp,
                                                  float* __restrict__ out) {
    const int s = blockIdx.x, tid = threadIdx.x;
    const int l = tid & 63, wv = tid >> 6;
    const int l15 = l & 15, lg = l >> 4;
    f4 acc[2][4];
    #pragma unroll
    for (int rt = 0; rt < 2; ++rt)
        #pragma unroll
        for (int ct = 0; ct < 4; ++ct) acc[rt][ct] = (f4){0.f, 0.f, 0.f, 0.f};
    float dnp[2] = {0.f, 0.f};
    const float*    Ab0 = dvecs + (size_t)s * NU * ND + (size_t)l15 * ND + lg * 8;
    const _Float16* Bb  = bpk + (size_t)(wv * 4) * 16 * 1024 + l * 8;
    for (int t = 0; t < 16; ++t) {
        half8 bh[4], bl[4];
        #pragma unroll
        for (int ct = 0; ct < 4; ++ct) {
            const _Float16* p = Bb + (size_t)(ct * 16 + t) * 1024;
            bh[ct] = *(const half8*)p;
            bl[ct] = *(const half8*)(p + 512);
        }
        half8 ah[2], al[2];
        #pragma unroll
        for (int rt = 0; rt < 2; ++rt) {
            const float* ap = Ab0 + rt * 16 * ND + t * 32;
            f4 a0 = *(const f4*)ap, a1 = *(const f4*)(ap + 4);
            dnp[rt] += a0[0]*a0[0] + a0[1]*a0[1] + a0[2]*a0[2] + a0[3]*a0[3]
                     + a1[0]*a1[0] + a1[1]*a1[1] + a1[2]*a1[2] + a1[3]*a1[3];
            #pragma unroll
            for (int i = 0; i < 4; ++i) {
                _Float16 h0 = (_Float16)a0[i];
                ah[rt][i]     = h0; al[rt][i]     = (_Float16)(a0[i] - (float)h0);
                _Float16 h1 = (_Float16)a1[i];
                ah[rt][4 + i] = h1; al[rt][4 + i] = (_Float16)(a1[i] - (float)h1);
            }
        }
        #pragma unroll
        for (int ct = 0; ct < 4; ++ct)
            #pragma unroll
            for (int rt = 0; rt < 2; ++rt) {
                acc[rt][ct] = __builtin_amdgcn_mfma_f32_16x16x32_f16(ah[rt], bh[ct], acc[rt][ct], 0, 0, 0);
                acc[rt][ct] = __builtin_amdgcn_mfma_f32_16x16x32_f16(ah[rt], bl[ct], acc[rt][ct], 0, 0, 0);
                acc[rt][ct] = __builtin_amdgcn_mfma_f32_16x16x32_f16(al[rt], bh[ct], acc[rt][ct], 0, 0, 0);
                acc[rt][ct] = __builtin_amdgcn_mfma_f32_16x16x32_f16(al[rt], bl[ct], acc[rt][ct], 0, 0, 0);
            }
    }
    #pragma unroll
    for (int rt = 0; rt < 2; ++rt) {
        dnp[rt] += __shfl_xor(dnp[rt], 16);
        dnp[rt] += __shfl_xor(dnp[rt], 32);
    }
    __shared__ float sDn2[32], sSelf[32], sMax[8][32], sSum[8][32], sRow[32];
    if (wv == 0 && l < 16) { sDn2[l15] = dnp[0]; sDn2[16 + l15] = dnp[1]; }
    __syncthreads();
    const float w = wp[0], bb = bp[0];
    const float cn2s = cn2[s];
    float dv[2][4];
    #pragma unroll
    for (int rt = 0; rt < 2; ++rt)
        #pragma unroll
        for (int r = 0; r < 4; ++r) dv[rt][r] = sDn2[rt * 16 + lg * 4 + r];
    const bool owner = (wv == (s >> 6)) && (l15 == (s & 15));
    const int  ctd   = (s >> 4) & 3;
    float dotc[2][4];
    #pragma unroll
    for (int ct = 0; ct < 4; ++ct)
        if (ct == ctd)
            #pragma unroll
            for (int rt = 0; rt < 2; ++rt)
                #pragma unroll
                for (int r = 0; r < 4; ++r) dotc[rt][r] = acc[rt][ct][r];
    #pragma unroll
    for (int ct = 0; ct < 4; ++ct) {
        const float cv = cn2[wv * 64 + ct * 16 + l15];
        #pragma unroll
        for (int rt = 0; rt < 2; ++rt)
            #pragma unroll
            for (int r = 0; r < 4; ++r)
                acc[rt][ct][r] = w * (acc[rt][ct][r] / fmaxf(sqrtf(dv[rt][r] * cv), GEPS)) + bb;
    }
    if (owner) {
        #pragma unroll
        for (int rt = 0; rt < 2; ++rt)
            #pragma unroll
            for (int r = 0; r < 4; ++r) {
                const float d2  = dv[rt][r];
                const float num = (float)NU * dotc[rt][r] - d2;
                const float X   = (float)(NU * NU) * cn2s - 2.0f * NU * dotc[rt][r] + d2;
                const float den = fmaxf(sqrtf(d2) * sqrtf(X), GEPS * (NU - 1));
                const float ls  = w * (num / den) + bb;
                #pragma unroll
                for (int ct = 0; ct < 4; ++ct)
                    if (ct == ctd) acc[rt][ct][r] = ls;
                sSelf[rt * 16 + lg * 4 + r] = ls;
            }
    }
    #pragma unroll
    for (int rt = 0; rt < 2; ++rt)
        #pragma unroll
        for (int r = 0; r < 4; ++r) {
            float mx = -INFINITY;
            #pragma unroll
            for (int ct = 0; ct < 4; ++ct) mx = fmaxf(mx, acc[rt][ct][r]);
            mx = fmaxf(mx, __shfl_xor(mx, 1)); mx = fmaxf(mx, __shfl_xor(mx, 2));
            mx = fmaxf(mx, __shfl_xor(mx, 4)); mx = fmaxf(mx, __shfl_xor(mx, 8));
            float se = 0.f;
            #pragma unroll
            for (int ct = 0; ct < 4; ++ct) se += expf(acc[rt][ct][r] - mx);
            se += __shfl_xor(se, 1); se += __shfl_xor(se, 2);
            se += __shfl_xor(se, 4); se += __shfl_xor(se, 8);
            if (l15 == 0) {
                sMax[wv][rt * 16 + lg * 4 + r] = mx;
                sSum[wv][rt * 16 + lg * 4 + r] = se;
            }
        }
    __syncthreads();
    if (tid < 32) {
        float M = -INFINITY;
        #pragma unroll
        for (int v = 0; v < 8; ++v) M = fmaxf(M, sMax[v][tid]);
        float S = 0.f;
        #pragma unroll
        for (int v = 0; v < 8; ++v) S += sSum[v][tid] * expf(sMax[v][tid] - M);
        sRow[tid] = logf(S) + M - sSelf[tid];
    }
    __syncthreads();
    if (tid == 0) {
        float tot = 0.f;
        #pragma unroll
        for (int u2 = 0; u2 < 32; ++u2) tot += sRow[u2];
        atomicAdd(out, tot);
    }
}

extern "C" void kernel_launch(void* const* d_in, const int* in_sizes, int n_in,
                              void* d_out, int out_size, void* d_ws, size_t ws_size,
                              hipStream_t stream) {
    const float* dvecs = (const float*)d_in[0];
    const float* w     = (const float*)d_in[1];
    const float* b     = (const float*)d_in[2];
    float* out = (float*)d_out;

    const size_t bpk_b = (size_t)32 * 16 * 1024 * sizeof(_Float16);     // 1 MiB
    const size_t cn2_b = (size_t)NS * sizeof(float);
    const size_t dn2_b = (size_t)NS * NU * sizeof(float);
    const size_t apk_b = (size_t)NS * 2 * 16 * 1024 * sizeof(_Float16); // 33.5 MiB
    const size_t need  = bpk_b + cn2_b + dn2_b + apk_b;

    char* p = (char*)d_ws;
    _Float16* bpk = (_Float16*)p;                 p += bpk_b;
    float*    cn2 = (float*)p;                    p += cn2_b;
    float*    dn2 = (float*)p;                    p += dn2_b;
    _Float16* apk = (_Float16*)p;

    hipMemsetAsync(d_out, 0, sizeof(float), stream);
    if (ws_size >= need) {
        prep_full<<<NS, 256, 0, stream>>>(dvecs, bpk, cn2, dn2, apk);
        ge2e_full<<<NS, 512, 0, stream>>>(apk, bpk, cn2, dn2, w, b, out);
    } else {
        prep_fb<<<NS, 256, 0, stream>>>(dvecs, bpk, cn2);
        ge2e_fb<<<NS, 512, 0, stream>>>(dvecs, bpk, cn2, w, b, out);
    }
}